// Round 16
// baseline (42.571 us; speedup 1.0000x reference)
//
#include <hip/hip_runtime.h>

#define COLS   8192
#define LEVELS 8
#define TPB    512

typedef float f4_t __attribute__((ext_vector_type(4)));

__device__ __forceinline__ void nt_store4(float* p, const float4 v) {
    f4_t w; w.x = v.x; w.y = v.y; w.z = v.z; w.w = v.w;
    __builtin_nontemporal_store(w, reinterpret_cast<f4_t*>(p));
}

// LDS-only barrier: waits LDS ops, lets global (vmcnt) ops stay in flight.
__device__ __forceinline__ void bar_lds() {
    asm volatile("s_waitcnt lgkmcnt(0)" ::: "memory");
    __builtin_amdgcn_sched_barrier(0);
    __builtin_amdgcn_s_barrier();
    __builtin_amdgcn_sched_barrier(0);
}

// R13 (best, 42.2us) + T14 issue-early/consume-late on the synthesis reads:
// after the full sync, all S1(d1)/S0(d0) global loads are issued into
// registers; the pure-LDS S3/S2 phases hide their latency (bar_lds waits
// lgkmcnt only, so the vmcnt loads stay in flight across barriers).
__global__ __launch_bounds__(TPB) void despawn_kernel(
    const float* __restrict__ x, const float* __restrict__ scaling,
    float* __restrict__ out, int rows)
{
    __shared__ __align__(16) float B[COLS / 2];   // 16 KB
    __shared__ __align__(16) float C[COLS / 4];   // 8 KB
    __shared__ __align__(16) float D[COLS / 4];   // 8 KB
    __shared__ float filt[LEVELS * 4];

    const int row = blockIdx.x;
    const int tid = threadIdx.x;

    if (tid < LEVELS * 4) filt[tid] = scaling[tid];
    bar_lds();

    const float* __restrict__ xg       = x + (size_t)row * COLS;
    float* __restrict__       out_rec  = out + (size_t)row * COLS;
    float* __restrict__       out_coef = out + (size_t)rows * COLS + (size_t)row * COLS;

    // ---------------- analysis level 0 (global float4, 4 outputs/thread) ----
    {
        const float h0 = filt[0], h1 = filt[1], h2 = filt[2], h3 = filt[3];
        const float g0 = h3, g1 = -h2, g2 = h1, g3 = -h0;
        const float4* __restrict__ xg4 = reinterpret_cast<const float4*>(xg);
        const int q8 = COLS / 8, qm = COLS / 4 - 1;
        for (int i = tid; i < q8; i += TPB) {
            const float4 va = xg4[(2 * i - 1) & qm];
            const float4 vb = xg4[2 * i];
            const float4 vc = xg4[2 * i + 1];
            float4 dv, av;
            dv.x = g0*vb.x + g1*va.w + g2*va.z + g3*va.y;
            av.x = h0*vb.x + h1*va.w + h2*va.z + h3*va.y;
            dv.y = g0*vb.z + g1*vb.y + g2*vb.x + g3*va.w;
            av.y = h0*vb.z + h1*vb.y + h2*vb.x + h3*va.w;
            dv.z = g0*vc.x + g1*vb.w + g2*vb.z + g3*vb.y;
            av.z = h0*vc.x + h1*vb.w + h2*vb.z + h3*vb.y;
            dv.w = g0*vc.z + g1*vc.y + g2*vc.x + g3*vb.w;
            av.w = h0*vc.z + h1*vc.y + h2*vc.x + h3*vb.w;
            reinterpret_cast<float4*>(out_coef)[i] = dv;   // d0: CACHED (re-read)
            reinterpret_cast<float4*>(B)[i]        = av;
        }
        bar_lds();
    }

    // ---------------- analysis levels 1..3 ---------------------------------
    int n = COLS / 2, coff = COLS / 2, dOff = 0;
    float* cur = B;
    float* nxt = C;
    for (int lev = 1; lev <= 3; ++lev) {
        const float h0 = filt[4*lev+0], h1 = filt[4*lev+1],
                    h2 = filt[4*lev+2], h3 = filt[4*lev+3];
        const float g0 = h3, g1 = -h2, g2 = h1, g3 = -h0;
        const int half = n >> 1, qq = half >> 2, qm = (n >> 2) - 1;
        const float4* c4 = reinterpret_cast<const float4*>(cur);
        float* ob = out_coef + coff;
        float4* n4 = reinterpret_cast<float4*>(nxt);
        float4* D4 = reinterpret_cast<float4*>(D + dOff);
        const bool toD = (lev >= 2);
        for (int p = tid; p < qq; p += TPB) {
            const float4 va = c4[(2 * p - 1) & qm];
            const float4 vb = c4[2 * p];
            const float4 vc = c4[2 * p + 1];
            float4 dv, av;
            dv.x = g0*vb.x + g1*va.w + g2*va.z + g3*va.y;
            av.x = h0*vb.x + h1*va.w + h2*va.z + h3*va.y;
            dv.y = g0*vb.z + g1*vb.y + g2*vb.x + g3*va.w;
            av.y = h0*vb.z + h1*vb.y + h2*vb.x + h3*va.w;
            dv.z = g0*vc.x + g1*vb.w + g2*vb.z + g3*vb.y;
            av.z = h0*vc.x + h1*vb.w + h2*vb.z + h3*vb.y;
            dv.w = g0*vc.z + g1*vc.y + g2*vc.x + g3*vb.w;
            av.w = h0*vc.z + h1*vc.y + h2*vc.x + h3*vb.w;
            if (toD) {
                nt_store4(ob + 4*p, dv);   // d2/d3: never re-read from global
                D4[p] = dv;
            } else {
                reinterpret_cast<float4*>(ob)[p] = dv;   // d1: CACHED (re-read)
            }
            n4[p] = av;
        }
        bar_lds();
        coff += half;
        if (toD) dOff += half;
        n = half;
        float* t = cur; cur = nxt; nxt = t;
    }
    // approx(512) now in C (cur == C)

    // ---------------- wave-0 tail: levels 4..7 both directions --------------
    if (tid < 64) {
        float* acur = C;
        float* anxt = B;
        int nn = 512, coffW = 7680, dW = 1536;
        for (int lev = 4; lev <= 7; ++lev) {
            const float h0 = filt[4*lev+0], h1 = filt[4*lev+1],
                        h2 = filt[4*lev+2], h3 = filt[4*lev+3];
            const float g0 = h3, g1 = -h2, g2 = h1, g3 = -h0;
            const int half = nn >> 1, mask = nn - 1;
            for (int i = tid; i < half; i += 64) {
                const int b = 2 * i;
                const float x0 = acur[b];
                const float x1 = acur[(b - 1) & mask];
                const float x2 = acur[(b - 2) & mask];
                const float x3 = acur[(b - 3) & mask];
                const float d = g0*x0 + g1*x1 + g2*x2 + g3*x3;
                const float a = h0*x0 + h1*x1 + h2*x2 + h3*x3;
                D[dW + i] = d;
                __builtin_nontemporal_store(d, &out_coef[coffW + i]);
                if (lev == 7) {
                    D[2016 + i] = a;
                    __builtin_nontemporal_store(a, &out_coef[8160 + i]);
                }
                else          anxt[i] = a;
            }
            __builtin_amdgcn_wave_barrier();
            coffW += half; dW += half; nn = half;
            float* t = acur; acur = anxt; anxt = t;
        }
        int mS = 32, dS = 1984;
        const float* aprevW = D + 2016;
        for (int lev = 7; lev >= 4; --lev) {
            const float h0 = filt[4*lev+0], h1 = filt[4*lev+1],
                        h2 = filt[4*lev+2], h3 = filt[4*lev+3];
            const float g0 = h3, g1 = -h2, g2 = h1, g3 = -h0;
            const int mm = mS - 1;
            float* recW = (lev & 1) ? B : C;
            for (int j = tid; j < mS; j += 64) {
                const float dj  = D[dS + j];
                const float dj1 = D[dS + ((j + 1) & mm)];
                const float dj2 = D[dS + ((j + 2) & mm)];
                const float aj  = aprevW[j];
                const float aj1 = aprevW[(j + 1) & mm];
                const float aj2 = aprevW[(j + 2) & mm];
                recW[2*j]     = g0*dj  + g2*dj1 + h0*aj  + h2*aj1;
                recW[2*j + 1] = g1*dj1 + g3*dj2 + h1*aj1 + h3*aj2;
            }
            __builtin_amdgcn_wave_barrier();
            aprevW = recW; mS <<= 1; dS -= mS;
        }
    }
    __syncthreads();   // FULL drain: d0/d1 stores visible before re-read
    // rec4(512) in C

    // ---------------- T14 prefetch: issue S1/S0 d-reads NOW ----------------
    // They stay in flight across the pure-LDS S3/S2 phases (bar_lds waits
    // lgkmcnt only). Statically indexed via unrolled loops (no scratch).
    const float2* __restrict__ d1g = reinterpret_cast<const float2*>(out_coef + 4096);
    const float2* __restrict__ d0g = reinterpret_cast<const float2*>(out_coef);
    float2 pf1a[2], pf1b[2], pf0a[4], pf0b[4];
    #pragma unroll
    for (int i = 0; i < 2; ++i) {
        const int p = tid + i * TPB;            // mp=1024
        pf1a[i] = d1g[p];
        pf1b[i] = d1g[(p + 1) & 1023];
    }
    #pragma unroll
    for (int i = 0; i < 4; ++i) {
        const int p = tid + i * TPB;            // mp=2048
        pf0a[i] = d0g[p];
        pf0b[i] = d0g[(p + 1) & 2047];
    }

    // ---------------- S3: m=512, d3 from LDS, rec4 in C -> rec3 in B --------
    {
        const float h0=filt[12],h1=filt[13],h2=filt[14],h3=filt[15];
        const float g0=h3,g1=-h2,g2=h1,g3=-h0;
        const float2* dL = reinterpret_cast<const float2*>(D + 1024);
        const float2* a2 = reinterpret_cast<const float2*>(C);
        for (int p = tid; p < 256; p += TPB) {
            const float2 dv0 = dL[p];
            const float2 dv1 = dL[(p + 1) & 255];
            const float2 av0 = a2[p];
            const float2 av1 = a2[(p + 1) & 255];
            const float r0 = g0*dv0.x + g2*dv0.y + h0*av0.x + h2*av0.y;
            const float r1 = g1*dv0.y + g3*dv1.x + h1*av0.y + h3*av1.x;
            const float r2 = g0*dv0.y + g2*dv1.x + h0*av0.y + h2*av1.x;
            const float r3 = g1*dv1.x + g3*dv1.y + h1*av1.x + h3*av1.y;
            reinterpret_cast<float4*>(B)[p] = make_float4(r0, r1, r2, r3);
        }
        bar_lds();
    }
    // ---------------- S2: m=1024, d2 from LDS, rec3 in B -> rec2 in C -------
    {
        const float h0=filt[8],h1=filt[9],h2=filt[10],h3=filt[11];
        const float g0=h3,g1=-h2,g2=h1,g3=-h0;
        const float2* dL = reinterpret_cast<const float2*>(D);
        const float2* a2 = reinterpret_cast<const float2*>(B);
        for (int p = tid; p < 512; p += TPB) {
            const float2 dv0 = dL[p];
            const float2 dv1 = dL[(p + 1) & 511];
            const float2 av0 = a2[p];
            const float2 av1 = a2[(p + 1) & 511];
            const float r0 = g0*dv0.x + g2*dv0.y + h0*av0.x + h2*av0.y;
            const float r1 = g1*dv0.y + g3*dv1.x + h1*av0.y + h3*av1.x;
            const float r2 = g0*dv0.y + g2*dv1.x + h0*av0.y + h2*av1.x;
            const float r3 = g1*dv1.x + g3*dv1.y + h1*av1.x + h3*av1.y;
            reinterpret_cast<float4*>(C)[p] = make_float4(r0, r1, r2, r3);
        }
        bar_lds();
    }
    // ---------------- S1: m=2048, d1 PREFETCHED, rec2 in C -> rec1 in B -----
    {
        const float h0=filt[4],h1=filt[5],h2=filt[6],h3=filt[7];
        const float g0=h3,g1=-h2,g2=h1,g3=-h0;
        const float2* a2 = reinterpret_cast<const float2*>(C);
        #pragma unroll
        for (int i = 0; i < 2; ++i) {
            const int p = tid + i * TPB;
            const float2 dv0 = pf1a[i];
            const float2 dv1 = pf1b[i];
            const float2 av0 = a2[p];
            const float2 av1 = a2[(p + 1) & 1023];
            const float r0 = g0*dv0.x + g2*dv0.y + h0*av0.x + h2*av0.y;
            const float r1 = g1*dv0.y + g3*dv1.x + h1*av0.y + h3*av1.x;
            const float r2 = g0*dv0.y + g2*dv1.x + h0*av0.y + h2*av1.x;
            const float r3 = g1*dv1.x + g3*dv1.y + h1*av1.x + h3*av1.y;
            reinterpret_cast<float4*>(B)[p] = make_float4(r0, r1, r2, r3);
        }
        bar_lds();
    }
    // ---------------- S0: m=4096, d0 PREFETCHED, rec1 in B -> out (nt) ------
    {
        const float h0=filt[0],h1=filt[1],h2=filt[2],h3=filt[3];
        const float g0=h3,g1=-h2,g2=h1,g3=-h0;
        const float2* a2 = reinterpret_cast<const float2*>(B);
        #pragma unroll
        for (int i = 0; i < 4; ++i) {
            const int p = tid + i * TPB;
            const float2 dv0 = pf0a[i];
            const float2 dv1 = pf0b[i];
            const float2 av0 = a2[p];
            const float2 av1 = a2[(p + 1) & 2047];
            const float r0 = g0*dv0.x + g2*dv0.y + h0*av0.x + h2*av0.y;
            const float r1 = g1*dv0.y + g3*dv1.x + h1*av0.y + h3*av1.x;
            const float r2 = g0*dv0.y + g2*dv1.x + h0*av0.y + h2*av1.x;
            const float r3 = g1*dv1.x + g3*dv1.y + h1*av1.x + h3*av1.y;
            nt_store4(out_rec + 4*p, make_float4(r0, r1, r2, r3));
        }
    }
}

extern "C" void kernel_launch(void* const* d_in, const int* in_sizes, int n_in,
                              void* d_out, int out_size, void* d_ws, size_t ws_size,
                              hipStream_t stream) {
    const float* x       = (const float*)d_in[0];
    const float* scaling = (const float*)d_in[1];
    float* out           = (float*)d_out;
    const int rows = in_sizes[0] / COLS;
    despawn_kernel<<<rows, TPB, 0, stream>>>(x, scaling, out, rows);
}